// Round 16
// baseline (648.212 us; speedup 1.0000x reference)
//
#include <hip/hip_runtime.h>
#include <math.h>

#define S_ 257
#define D_ 512
#define MB_ 5  // ceil(257/64)

typedef __attribute__((ext_vector_type(8))) short bf16x8;
typedef __attribute__((ext_vector_type(4))) float f32x4;

__device__ __forceinline__ unsigned pack2(unsigned short a, unsigned short b) {
  return (unsigned)a | ((unsigned)b << 16);
}
__device__ __forceinline__ void split_hl(float x, unsigned short& h,
                                         unsigned short& l) {
  const unsigned u = __float_as_uint(x);
  h = (unsigned short)(u >> 16);
  const float xh = __uint_as_float(u & 0xFFFF0000u);
  l = (unsigned short)(__float_as_uint(x - xh) >> 16);
}

// ---------------- embed ------------------------------------------------------
__global__ __launch_bounds__(256) void embed_kernel(
    const float* __restrict__ in_x, const float* __restrict__ emb_w,
    const float* __restrict__ emb_b, const float* __restrict__ pos_emb,
    const float* __restrict__ cls_emb, float* __restrict__ src) {
  const int row = blockIdx.x;
  const int tid = threadIdx.x;
  if (row == 0) {
    for (int j = tid; j < D_; j += 256) src[j] = cls_emb[j] + pos_emb[j];
    return;
  }
  __shared__ __align__(16) float xr[64];
  if (tid < 64) xr[tid] = in_x[(row - 1) * 64 + tid];
  __syncthreads();
  for (int j = tid; j < D_; j += 256) {
    float acc = emb_b[j];
#pragma unroll 8
    for (int k = 0; k < 64; ++k) acc += xr[k] * emb_w[k * D_ + j];
    src[row * D_ + j] = acc + pos_emb[row * D_ + j];
  }
}

// ---------------- MFMA GEMM, 64x64 tile, hi/lo bf16 --------------------------
// SPLITK=true : outp[bz][m][n] = partial sums over k-slice.
// SPLITK=false: outp[m][n] = full GEMM + bias (+relu) - removes reduce pass.
template <bool TRANSB, bool RELU, bool SPLITK>
__global__ __launch_bounds__(256, 2) void gemm_mfma(
    const float* __restrict__ A, const float* __restrict__ B,
    const float* __restrict__ bias, float* __restrict__ outp, int M, int N,
    int K, int kslice, int nb, int MNtot) {
  const int q = gridDim.x >> 3;
  const int orig = blockIdx.x;
  const int logical = (orig & 7) * q + (orig >> 3);
  const int by = logical % MB_;
  const int t2 = logical / MB_;
  const int bx = t2 % nb;
  const int bz = t2 / nb;
  const int m0 = by * 64, n0 = bx * 64, kbeg = bz * kslice;

  __shared__ __align__(16) unsigned short Ah[64][40];
  __shared__ __align__(16) unsigned short Al[64][40];
  __shared__ __align__(16) unsigned short Bh[64][40];
  __shared__ __align__(16) unsigned short Bl[64][40];

  const int tid = threadIdx.x;
  const int sm = tid & 63;
  const int sk = (tid >> 6) * 8;
  const int bk = tid >> 3;
  const int bn = (tid & 7) * 8;

  const int lane = tid & 63;
  const int wave = tid >> 6;
  const int wr = wave >> 1;
  const int wc = wave & 1;
  const int fr = lane & 15;
  const int ko = (lane >> 4) * 8;

  const f32x4 zf = {0.f, 0.f, 0.f, 0.f};
  f32x4 acc[2][2] = {{zf, zf}, {zf, zf}};

  const int nt = kslice >> 5;
  for (int t = 0; t < nt; ++t) {
    const int k0 = kbeg + t * 32;
    {
      float f[8];
      const int gm = m0 + sm;
      if (gm < M) {
        const float4 a0 = *reinterpret_cast<const float4*>(
            &A[(size_t)gm * K + k0 + sk]);
        const float4 a1 = *reinterpret_cast<const float4*>(
            &A[(size_t)gm * K + k0 + sk + 4]);
        f[0] = a0.x; f[1] = a0.y; f[2] = a0.z; f[3] = a0.w;
        f[4] = a1.x; f[5] = a1.y; f[6] = a1.z; f[7] = a1.w;
      } else {
#pragma unroll
        for (int i = 0; i < 8; ++i) f[i] = 0.f;
      }
      unsigned short h[8], l[8];
#pragma unroll
      for (int i = 0; i < 8; ++i) split_hl(f[i], h[i], l[i]);
      *reinterpret_cast<uint4*>(&Ah[sm][sk]) =
          make_uint4(pack2(h[0], h[1]), pack2(h[2], h[3]), pack2(h[4], h[5]),
                     pack2(h[6], h[7]));
      *reinterpret_cast<uint4*>(&Al[sm][sk]) =
          make_uint4(pack2(l[0], l[1]), pack2(l[2], l[3]), pack2(l[4], l[5]),
                     pack2(l[6], l[7]));
    }
    if (TRANSB) {
      const float4 b0 = *reinterpret_cast<const float4*>(
          &B[(size_t)(n0 + sm) * K + k0 + sk]);
      const float4 b1 = *reinterpret_cast<const float4*>(
          &B[(size_t)(n0 + sm) * K + k0 + sk + 4]);
      float f[8] = {b0.x, b0.y, b0.z, b0.w, b1.x, b1.y, b1.z, b1.w};
      unsigned short h[8], l[8];
#pragma unroll
      for (int i = 0; i < 8; ++i) split_hl(f[i], h[i], l[i]);
      *reinterpret_cast<uint4*>(&Bh[sm][sk]) =
          make_uint4(pack2(h[0], h[1]), pack2(h[2], h[3]), pack2(h[4], h[5]),
                     pack2(h[6], h[7]));
      *reinterpret_cast<uint4*>(&Bl[sm][sk]) =
          make_uint4(pack2(l[0], l[1]), pack2(l[2], l[3]), pack2(l[4], l[5]),
                     pack2(l[6], l[7]));
    } else {
      const float4 b0 = *reinterpret_cast<const float4*>(
          &B[(size_t)(k0 + bk) * N + n0 + bn]);
      const float4 b1 = *reinterpret_cast<const float4*>(
          &B[(size_t)(k0 + bk) * N + n0 + bn + 4]);
      const float f[8] = {b0.x, b0.y, b0.z, b0.w, b1.x, b1.y, b1.z, b1.w};
#pragma unroll
      for (int i = 0; i < 8; ++i) {
        unsigned short h, l;
        split_hl(f[i], h, l);
        Bh[bn + i][bk] = h;
        Bl[bn + i][bk] = l;
      }
    }
    __syncthreads();
    bf16x8 ah[2], al_[2], bh[2], bl_[2];
#pragma unroll
    for (int mf = 0; mf < 2; ++mf) {
      ah[mf] = *reinterpret_cast<const bf16x8*>(&Ah[wr * 32 + mf * 16 + fr][ko]);
      al_[mf] =
          *reinterpret_cast<const bf16x8*>(&Al[wr * 32 + mf * 16 + fr][ko]);
      bh[mf] = *reinterpret_cast<const bf16x8*>(&Bh[wc * 32 + mf * 16 + fr][ko]);
      bl_[mf] =
          *reinterpret_cast<const bf16x8*>(&Bl[wc * 32 + mf * 16 + fr][ko]);
    }
#pragma unroll
    for (int mf = 0; mf < 2; ++mf)
#pragma unroll
      for (int nf = 0; nf < 2; ++nf) {
        acc[mf][nf] = __builtin_amdgcn_mfma_f32_16x16x32_bf16(
            ah[mf], bh[nf], acc[mf][nf], 0, 0, 0);
        acc[mf][nf] = __builtin_amdgcn_mfma_f32_16x16x32_bf16(
            ah[mf], bl_[nf], acc[mf][nf], 0, 0, 0);
        acc[mf][nf] = __builtin_amdgcn_mfma_f32_16x16x32_bf16(
            al_[mf], bh[nf], acc[mf][nf], 0, 0, 0);
      }
    __syncthreads();
  }

  float* pb = SPLITK ? (outp + (size_t)bz * MNtot) : outp;
#pragma unroll
  for (int mf = 0; mf < 2; ++mf)
#pragma unroll
    for (int nf = 0; nf < 2; ++nf) {
      const int n = n0 + wc * 32 + nf * 16 + fr;
      const float bv = SPLITK ? 0.f : bias[n];
#pragma unroll
      for (int j = 0; j < 4; ++j) {
        const int m = m0 + wr * 32 + mf * 16 + (lane >> 4) * 4 + j;
        if (m < M) {
          float v = acc[mf][nf][j] + bv;
          if (RELU) v = fmaxf(v, 0.f);
          pb[(size_t)m * N + n] = v;
        }
      }
    }
}

// ---------------- split-K reduce + bias + residual + LayerNorm --------------
__global__ __launch_bounds__(256) void reduce_ln(const float* __restrict__ part,
                                                 const float* __restrict__ bias,
                                                 float* __restrict__ io,
                                                 const float* __restrict__ g,
                                                 const float* __restrict__ b,
                                                 int S) {
  const int row = blockIdx.x;
  const int tid = threadIdx.x;
  const size_t base = (size_t)row * D_;
  float x0 = io[base + tid] + bias[tid];
  float x1 = io[base + 256 + tid] + bias[256 + tid];
  for (int s = 0; s < S; ++s) {
    x0 += part[(size_t)s * (S_ * D_) + base + tid];
    x1 += part[(size_t)s * (S_ * D_) + base + 256 + tid];
  }
  __shared__ float redA[4], redB[4];
  float s = x0 + x1;
#pragma unroll
  for (int off = 32; off > 0; off >>= 1) s += __shfl_down(s, off);
  if ((tid & 63) == 0) redA[tid >> 6] = s;
  __syncthreads();
  const float mu = (redA[0] + redA[1] + redA[2] + redA[3]) * (1.f / 512.f);
  const float d0 = x0 - mu, d1 = x1 - mu;
  float qv = d0 * d0 + d1 * d1;
#pragma unroll
  for (int off = 32; off > 0; off >>= 1) qv += __shfl_down(qv, off);
  if ((tid & 63) == 0) redB[tid >> 6] = qv;
  __syncthreads();
  const float var = (redB[0] + redB[1] + redB[2] + redB[3]) * (1.f / 512.f);
  const float inv = rsqrtf(var + 1e-5f);
  io[base + tid] = d0 * inv * g[tid] + b[tid];
  io[base + 256 + tid] = d1 * inv * g[256 + tid] + b[256 + tid];
}

// ---------------- attention (one block per (query, head)) ------------------
__global__ __launch_bounds__(256) void attn_kernel(const float* __restrict__ qkv,
                                                   float* __restrict__ o) {
  const int sq = blockIdx.x;
  const int h = blockIdx.y;
  const int tid = threadIdx.x;
  __shared__ __align__(16) float qv[64];
  __shared__ float sc[S_];
  __shared__ float redA[4], redB[4];
  __shared__ float pv[4][64];
  if (tid < 64) qv[tid] = qkv[(size_t)sq * 1536 + h * 64 + tid];
  __syncthreads();
  for (int j = tid; j < S_; j += 256) {
    const float4* kr =
        reinterpret_cast<const float4*>(&qkv[(size_t)j * 1536 + D_ + h * 64]);
    const float4* qr = reinterpret_cast<const float4*>(qv);
    float acc = 0.f;
#pragma unroll
    for (int d = 0; d < 16; ++d) {
      const float4 kk = kr[d], qq = qr[d];
      acc += kk.x * qq.x + kk.y * qq.y + kk.z * qq.z + kk.w * qq.w;
    }
    sc[j] = acc * 0.125f;
  }
  __syncthreads();
  float lm = -1e30f;
  for (int j = tid; j < S_; j += 256) lm = fmaxf(lm, sc[j]);
#pragma unroll
  for (int off = 32; off > 0; off >>= 1) lm = fmaxf(lm, __shfl_down(lm, off));
  if ((tid & 63) == 0) redA[tid >> 6] = lm;
  __syncthreads();
  const float M = fmaxf(fmaxf(redA[0], redA[1]), fmaxf(redA[2], redA[3]));
  float ls = 0.f;
  for (int j = tid; j < S_; j += 256) {
    const float p = __expf(sc[j] - M);
    sc[j] = p;
    ls += p;
  }
#pragma unroll
  for (int off = 32; off > 0; off >>= 1) ls += __shfl_down(ls, off);
  if ((tid & 63) == 0) redB[tid >> 6] = ls;
  __syncthreads();
  const float invS = 1.f / (redB[0] + redB[1] + redB[2] + redB[3]);
  const int d = tid & 63;
  const int ch = tid >> 6;
  float acc = 0.f;
  for (int j = ch; j < S_; j += 4)
    acc += sc[j] * qkv[(size_t)j * 1536 + 2 * D_ + h * 64 + d];
  pv[ch][d] = acc;
  __syncthreads();
  if (tid < 64)
    o[(size_t)sq * D_ + h * 64 + tid] =
        (pv[0][tid] + pv[1][tid] + pv[2][tid] + pv[3][tid]) * invS;
}

// ---------------- output head GEMV (split-d partials) -----------------------
__global__ __launch_bounds__(256) void gemv_kernel(const float* __restrict__ src0,
                                                   const float* __restrict__ out_w,
                                                   float* __restrict__ parts) {
  const int jc = blockIdx.x;
  const int dc = blockIdx.y;
  const int tid = threadIdx.x;
  __shared__ __align__(16) float s0[64];
  if (tid < 64) s0[tid] = src0[dc * 64 + tid];
  __syncthreads();
  const int j0 = jc * 1024 + tid * 4;
  float4 acc = make_float4(0.f, 0.f, 0.f, 0.f);
  for (int d = 0; d < 64; ++d) {
    const float sv = s0[d];
    const float4 w = *reinterpret_cast<const float4*>(
        &out_w[(size_t)(dc * 64 + d) * 65536 + j0]);
    acc.x += sv * w.x;
    acc.y += sv * w.y;
    acc.z += sv * w.z;
    acc.w += sv * w.w;
  }
  *reinterpret_cast<float4*>(&parts[(size_t)dc * 65536 + j0]) = acc;
}

// ---------------- logits = sum(8 gemv partials) + bias -----------------------
__global__ __launch_bounds__(256) void logits_reduce_kernel(
    const float* __restrict__ parts, const float* __restrict__ out_b,
    float* __restrict__ logits) {
  const int j = (blockIdx.x * 256 + threadIdx.x) * 4;
  float4 acc = *reinterpret_cast<const float4*>(&out_b[j]);
#pragma unroll
  for (int p = 0; p < 8; ++p) {
    const float4 v =
        *reinterpret_cast<const float4*>(&parts[(size_t)p * 65536 + j]);
    acc.x += v.x;
    acc.y += v.y;
    acc.z += v.z;
    acc.w += v.w;
  }
  *reinterpret_cast<float4*>(&logits[j]) = acc;
}

// ---------------- sinkhorn: wave-parallel butterfly --------------------------
__global__ __launch_bounds__(1024) void sinkhorn_kernel(
    const float* __restrict__ logits, float* __restrict__ out) {
  const int tid = threadIdx.x;
  const int tx = tid >> 5;
  const int ty = tid & 31;
  const int r0 = ty * 8, c0 = tx * 8;

  float E[8][8];
#pragma unroll
  for (int ii = 0; ii < 8; ++ii) {
    const int idx = (r0 + ii) * 256 + c0;
    const float4 a = *reinterpret_cast<const float4*>(&logits[idx]);
    const float4 b = *reinterpret_cast<const float4*>(&logits[idx + 4]);
    E[ii][0] = __expf(a.x);
    E[ii][1] = __expf(a.y);
    E[ii][2] = __expf(a.z);
    E[ii][3] = __expf(a.w);
    E[ii][4] = __expf(b.x);
    E[ii][5] = __expf(b.y);
    E[ii][6] = __expf(b.z);
    E[ii][7] = __expf(b.w);
  }

  __shared__ float partR[32][8][36];
  __shared__ int partI[32][8][36];
  __shared__ float uu[256];
  __shared__ int amax[256];

  float ul[8], vl[8];
#pragma unroll
  for (int ii = 0; ii < 8; ++ii) ul[ii] = 1.f;

  for (int it = 0; it < 20; ++it) {
#pragma unroll
    for (int jj = 0; jj < 8; ++jj) {
      float s = 0.f;
#pragma unroll
      for (int ii = 0; ii < 8; ++ii) s += E[ii][jj] * ul[ii];
#pragma unroll
      for (int m = 1; m < 32; m <<= 1) s += __shfl_xor(s, m, 64);
      vl[jj] = 1.f / s;
    }
#pragma unroll
    for (int ii = 0; ii < 8; ++ii) {
      float s = 0.f;
#pragma unroll
      for (int jj = 0; jj < 8; ++jj) s += E[ii][jj] * vl[jj];
      partR[tx][ii][ty] = s;
    }
    __syncthreads();
    {
      const int r = tid >> 2, qq = tid & 3;
      float s = 0.f;
#pragma unroll
      for (int p = 0; p < 8; ++p) s += partR[qq * 8 + p][r & 7][r >> 3];
      s += __shfl_xor(s, 1, 64);
      s += __shfl_xor(s, 2, 64);
      if (qq == 0) uu[r] = 1.f / s;
    }
    __syncthreads();
#pragma unroll
    for (int ii = 0; ii < 8; ++ii) ul[ii] = uu[r0 + ii];
  }

#pragma unroll
  for (int ii = 0; ii < 8; ++ii) {
    float vals[8];
    float best = -1.f;
    int bidx = 0;
#pragma unroll
    for (int jj = 0; jj < 8; ++jj) {
      const float pv = E[ii][jj] * ul[ii] * vl[jj];
      vals[jj] = pv;
      if (pv > best) {
        best = pv;
        bidx = c0 + jj;
      }
    }
    *reinterpret_cast<float4*>(&out[(r0 + ii) * 256 + c0]) =
        make_float4(vals[0], vals[1], vals[2], vals[3]);
    *reinterpret_cast<float4*>(&out[(r0 + ii) * 256 + c0 + 4]) =
        make_float4(vals[4], vals[5], vals[6], vals[7]);
    partR[tx][ii][ty] = best;
    partI[tx][ii][ty] = bidx;
  }
  __syncthreads();
  {
    const int r = tid >> 2, qq = tid & 3;
    float best = -1.f;
    int bi = 1 << 30;
#pragma unroll
    for (int p = 0; p < 8; ++p) {
      const float v = partR[qq * 8 + p][r & 7][r >> 3];
      const int ix = partI[qq * 8 + p][r & 7][r >> 3];
      if (v > best || (v == best && ix < bi)) {
        best = v;
        bi = ix;
      }
    }
#pragma unroll
    for (int m = 1; m < 4; m <<= 1) {
      const float ov = __shfl_xor(best, m, 64);
      const int oi = __shfl_xor(bi, m, 64);
      if (ov > best || (ov == best && oi < bi)) {
        best = ov;
        bi = oi;
      }
    }
    if (qq == 0) amax[r] = bi;
  }
  __syncthreads();
#pragma unroll
  for (int ii = 0; ii < 8; ++ii) {
    const int am = amax[r0 + ii];
    float4 h0, h1;
    h0.x = (c0 + 0 == am) ? 1.f : 0.f;
    h0.y = (c0 + 1 == am) ? 1.f : 0.f;
    h0.z = (c0 + 2 == am) ? 1.f : 0.f;
    h0.w = (c0 + 3 == am) ? 1.f : 0.f;
    h1.x = (c0 + 4 == am) ? 1.f : 0.f;
    h1.y = (c0 + 5 == am) ? 1.f : 0.f;
    h1.z = (c0 + 6 == am) ? 1.f : 0.f;
    h1.w = (c0 + 7 == am) ? 1.f : 0.f;
    *reinterpret_cast<float4*>(&out[65536 + (r0 + ii) * 256 + c0]) = h0;
    *reinterpret_cast<float4*>(&out[65536 + (r0 + ii) * 256 + c0 + 4]) = h1;
  }
}

// ---------------- host-side launch ------------------------------------------
extern "C" void kernel_launch(void* const* d_in, const int* in_sizes, int n_in,
                              void* d_out, int out_size, void* d_ws,
                              size_t ws_size, hipStream_t stream) {
  (void)in_sizes;
  (void)n_in;
  (void)out_size;
  (void)ws_size;
  const float* in_x = (const float*)d_in[0];
  const float* emb_w = (const float*)d_in[1];
  const float* emb_b = (const float*)d_in[2];
  const float* pos_emb = (const float*)d_in[3];
  const float* cls_emb = (const float*)d_in[4];
  const float* ipw = (const float*)d_in[5];
  const float* ipb = (const float*)d_in[6];
  const float* aow = (const float*)d_in[7];
  const float* aob = (const float*)d_in[8];
  const float* fw1 = (const float*)d_in[9];
  const float* fb1 = (const float*)d_in[10];
  const float* fw2 = (const float*)d_in[11];
  const float* fb2 = (const float*)d_in[12];
  const float* ln1g = (const float*)d_in[13];
  const float* ln1b = (const float*)d_in[14];
  const float* ln2g = (const float*)d_in[15];
  const float* ln2b = (const float*)d_in[16];
  const float* out_w = (const float*)d_in[17];
  const float* out_b = (const float*)d_in[18];
  float* out = (float*)d_out;
  float* ws = (float*)d_ws;

  float* src = ws;               // 131584
  float* qkv = ws + 131584;      // 394752
  float* attnO = ws + 526336;    // 131584
  float* ffh = ws + 657920;      // 526336
  float* logits = ws + 1184256;  // 65536
  float* part = ws + 1249792;    // max 8*131584 (proj/ff2 partials) / gemv
  float* gparts = part;

  embed_kernel<<<dim3(S_), dim3(256), 0, stream>>>(in_x, emb_w, emb_b, pos_emb,
                                                   cls_emb, src);
  for (int l = 0; l < 4; ++l) {
    // qkv: full-K (nt=16), fused bias -> no reduce dispatch
    gemm_mfma<true, false, false><<<dim3(24 * MB_), dim3(256), 0, stream>>>(
        src, ipw + (size_t)l * 1536 * 512, ipb + l * 1536, qkv, S_, 1536, 512,
        512, 24, 0);
    attn_kernel<<<dim3(S_, 8), dim3(256), 0, stream>>>(qkv, attnO);
    // proj: splitK8 (kslice 64, nt=2), 320 blocks
    gemm_mfma<true, false, true><<<dim3(8 * MB_ * 8), dim3(256), 0, stream>>>(
        attnO, aow + (size_t)l * 512 * 512, nullptr, part, S_, 512, 512, 64, 8,
        S_ * D_);
    reduce_ln<<<dim3(S_), dim3(256), 0, stream>>>(part, aob + l * 512, src,
                                                  ln1g + l * 512,
                                                  ln1b + l * 512, 8);
    // ff1: full-K (nt=16), fused bias+relu -> no reduce dispatch
    gemm_mfma<false, true, false><<<dim3(32 * MB_), dim3(256), 0, stream>>>(
        src, fw1 + (size_t)l * 512 * 2048, fb1 + l * 2048, ffh, S_, 2048, 512,
        512, 32, 0);
    // ff2: splitK8 (kslice 256, nt=8), 320 blocks
    gemm_mfma<false, false, true><<<dim3(8 * MB_ * 8), dim3(256), 0, stream>>>(
        ffh, fw2 + (size_t)l * 2048 * 512, nullptr, part, S_, 512, 2048, 256,
        8, S_ * D_);
    reduce_ln<<<dim3(S_), dim3(256), 0, stream>>>(part, fb2 + l * 512, src,
                                                  ln2g + l * 512,
                                                  ln2b + l * 512, 8);
  }
  gemv_kernel<<<dim3(64, 8), dim3(256), 0, stream>>>(src, out_w, gparts);
  logits_reduce_kernel<<<dim3(64), dim3(256), 0, stream>>>(gparts, out_b,
                                                           logits);
  sinkhorn_kernel<<<dim3(1), dim3(1024), 0, stream>>>(logits, out);
}

// Round 17
// 606.158 us; speedup vs baseline: 1.0694x; 1.0694x over previous
//
#include <hip/hip_runtime.h>
#include <math.h>

#define S_ 257
#define D_ 512
#define MB_ 5  // ceil(257/64)

typedef __attribute__((ext_vector_type(8))) short bf16x8;
typedef __attribute__((ext_vector_type(4))) float f32x4;

__device__ __forceinline__ unsigned pack2(unsigned short a, unsigned short b) {
  return (unsigned)a | ((unsigned)b << 16);
}
__device__ __forceinline__ void split_hl(float x, unsigned short& h,
                                         unsigned short& l) {
  const unsigned u = __float_as_uint(x);
  h = (unsigned short)(u >> 16);
  const float xh = __uint_as_float(u & 0xFFFF0000u);
  l = (unsigned short)(__float_as_uint(x - xh) >> 16);
}

// ---------------- embed ------------------------------------------------------
__global__ __launch_bounds__(256) void embed_kernel(
    const float* __restrict__ in_x, const float* __restrict__ emb_w,
    const float* __restrict__ emb_b, const float* __restrict__ pos_emb,
    const float* __restrict__ cls_emb, float* __restrict__ src) {
  const int row = blockIdx.x;
  const int tid = threadIdx.x;
  if (row == 0) {
    for (int j = tid; j < D_; j += 256) src[j] = cls_emb[j] + pos_emb[j];
    return;
  }
  __shared__ __align__(16) float xr[64];
  if (tid < 64) xr[tid] = in_x[(row - 1) * 64 + tid];
  __syncthreads();
  for (int j = tid; j < D_; j += 256) {
    float acc = emb_b[j];
#pragma unroll 8
    for (int k = 0; k < 64; ++k) acc += xr[k] * emb_w[k * D_ + j];
    src[row * D_ + j] = acc + pos_emb[row * D_ + j];
  }
}

// ---------------- MFMA split-K GEMM, 64x64 tile, hi/lo bf16 ------------------
template <bool TRANSB>
__global__ __launch_bounds__(256, 2) void gemm_mfma(
    const float* __restrict__ A, const float* __restrict__ B,
    float* __restrict__ part, int M, int N, int K, int kslice, int nb,
    int MNtot) {
  const int q = gridDim.x >> 3;
  const int orig = blockIdx.x;
  const int logical = (orig & 7) * q + (orig >> 3);
  const int by = logical % MB_;
  const int t2 = logical / MB_;
  const int bx = t2 % nb;
  const int bz = t2 / nb;
  const int m0 = by * 64, n0 = bx * 64, kbeg = bz * kslice;

  __shared__ __align__(16) unsigned short Ah[64][40];
  __shared__ __align__(16) unsigned short Al[64][40];
  __shared__ __align__(16) unsigned short Bh[64][40];
  __shared__ __align__(16) unsigned short Bl[64][40];

  const int tid = threadIdx.x;
  const int sm = tid & 63;
  const int sk = (tid >> 6) * 8;
  const int bk = tid >> 3;
  const int bn = (tid & 7) * 8;

  const int lane = tid & 63;
  const int wave = tid >> 6;
  const int wr = wave >> 1;
  const int wc = wave & 1;
  const int fr = lane & 15;
  const int ko = (lane >> 4) * 8;

  const f32x4 zf = {0.f, 0.f, 0.f, 0.f};
  f32x4 acc[2][2] = {{zf, zf}, {zf, zf}};

  const int nt = kslice >> 5;
  for (int t = 0; t < nt; ++t) {
    const int k0 = kbeg + t * 32;
    {
      float f[8];
      const int gm = m0 + sm;
      if (gm < M) {
        const float4 a0 = *reinterpret_cast<const float4*>(
            &A[(size_t)gm * K + k0 + sk]);
        const float4 a1 = *reinterpret_cast<const float4*>(
            &A[(size_t)gm * K + k0 + sk + 4]);
        f[0] = a0.x; f[1] = a0.y; f[2] = a0.z; f[3] = a0.w;
        f[4] = a1.x; f[5] = a1.y; f[6] = a1.z; f[7] = a1.w;
      } else {
#pragma unroll
        for (int i = 0; i < 8; ++i) f[i] = 0.f;
      }
      unsigned short h[8], l[8];
#pragma unroll
      for (int i = 0; i < 8; ++i) split_hl(f[i], h[i], l[i]);
      *reinterpret_cast<uint4*>(&Ah[sm][sk]) =
          make_uint4(pack2(h[0], h[1]), pack2(h[2], h[3]), pack2(h[4], h[5]),
                     pack2(h[6], h[7]));
      *reinterpret_cast<uint4*>(&Al[sm][sk]) =
          make_uint4(pack2(l[0], l[1]), pack2(l[2], l[3]), pack2(l[4], l[5]),
                     pack2(l[6], l[7]));
    }
    if (TRANSB) {
      const float4 b0 = *reinterpret_cast<const float4*>(
          &B[(size_t)(n0 + sm) * K + k0 + sk]);
      const float4 b1 = *reinterpret_cast<const float4*>(
          &B[(size_t)(n0 + sm) * K + k0 + sk + 4]);
      float f[8] = {b0.x, b0.y, b0.z, b0.w, b1.x, b1.y, b1.z, b1.w};
      unsigned short h[8], l[8];
#pragma unroll
      for (int i = 0; i < 8; ++i) split_hl(f[i], h[i], l[i]);
      *reinterpret_cast<uint4*>(&Bh[sm][sk]) =
          make_uint4(pack2(h[0], h[1]), pack2(h[2], h[3]), pack2(h[4], h[5]),
                     pack2(h[6], h[7]));
      *reinterpret_cast<uint4*>(&Bl[sm][sk]) =
          make_uint4(pack2(l[0], l[1]), pack2(l[2], l[3]), pack2(l[4], l[5]),
                     pack2(l[6], l[7]));
    } else {
      const float4 b0 = *reinterpret_cast<const float4*>(
          &B[(size_t)(k0 + bk) * N + n0 + bn]);
      const float4 b1 = *reinterpret_cast<const float4*>(
          &B[(size_t)(k0 + bk) * N + n0 + bn + 4]);
      const float f[8] = {b0.x, b0.y, b0.z, b0.w, b1.x, b1.y, b1.z, b1.w};
#pragma unroll
      for (int i = 0; i < 8; ++i) {
        unsigned short h, l;
        split_hl(f[i], h, l);
        Bh[bn + i][bk] = h;
        Bl[bn + i][bk] = l;
      }
    }
    __syncthreads();
    bf16x8 ah[2], al_[2], bh[2], bl_[2];
#pragma unroll
    for (int mf = 0; mf < 2; ++mf) {
      ah[mf] = *reinterpret_cast<const bf16x8*>(&Ah[wr * 32 + mf * 16 + fr][ko]);
      al_[mf] =
          *reinterpret_cast<const bf16x8*>(&Al[wr * 32 + mf * 16 + fr][ko]);
      bh[mf] = *reinterpret_cast<const bf16x8*>(&Bh[wc * 32 + mf * 16 + fr][ko]);
      bl_[mf] =
          *reinterpret_cast<const bf16x8*>(&Bl[wc * 32 + mf * 16 + fr][ko]);
    }
#pragma unroll
    for (int mf = 0; mf < 2; ++mf)
#pragma unroll
      for (int nf = 0; nf < 2; ++nf) {
        acc[mf][nf] = __builtin_amdgcn_mfma_f32_16x16x32_bf16(
            ah[mf], bh[nf], acc[mf][nf], 0, 0, 0);
        acc[mf][nf] = __builtin_amdgcn_mfma_f32_16x16x32_bf16(
            ah[mf], bl_[nf], acc[mf][nf], 0, 0, 0);
        acc[mf][nf] = __builtin_amdgcn_mfma_f32_16x16x32_bf16(
            al_[mf], bh[nf], acc[mf][nf], 0, 0, 0);
      }
    __syncthreads();
  }

  // C-write: D layout col=lane&15, row=(lane>>4)*4+j  [verified m89/m91]
  float* pb = part + (size_t)bz * MNtot;
#pragma unroll
  for (int mf = 0; mf < 2; ++mf)
#pragma unroll
    for (int nf = 0; nf < 2; ++nf) {
      const int n = n0 + wc * 32 + nf * 16 + fr;
#pragma unroll
      for (int j = 0; j < 4; ++j) {
        const int m = m0 + wr * 32 + mf * 16 + (lane >> 4) * 4 + j;
        if (m < M) pb[(size_t)m * N + n] = acc[mf][nf][j];
      }
    }
}

// ---------------- split-K reduce: + bias (+relu), elementwise ---------------
__global__ __launch_bounds__(256) void reduce_elem(const float* __restrict__ part,
                                                   const float* __restrict__ bias,
                                                   float* __restrict__ out,
                                                   int MN, int N, int S,
                                                   int relu) {
  const int i = (blockIdx.x * 256 + threadIdx.x) * 4;
  if (i >= MN) return;
  const float4 bb = *reinterpret_cast<const float4*>(&bias[i % N]);
  float4 acc = bb;
  for (int s = 0; s < S; ++s) {
    const float4 v = *reinterpret_cast<const float4*>(&part[(size_t)s * MN + i]);
    acc.x += v.x;
    acc.y += v.y;
    acc.z += v.z;
    acc.w += v.w;
  }
  if (relu) {
    acc.x = fmaxf(acc.x, 0.f);
    acc.y = fmaxf(acc.y, 0.f);
    acc.z = fmaxf(acc.z, 0.f);
    acc.w = fmaxf(acc.w, 0.f);
  }
  *reinterpret_cast<float4*>(&out[i]) = acc;
}

// ---------------- split-K reduce + bias + residual + LayerNorm --------------
__global__ __launch_bounds__(256) void reduce_ln(const float* __restrict__ part,
                                                 const float* __restrict__ bias,
                                                 float* __restrict__ io,
                                                 const float* __restrict__ g,
                                                 const float* __restrict__ b,
                                                 int S) {
  const int row = blockIdx.x;
  const int tid = threadIdx.x;
  const size_t base = (size_t)row * D_;
  float x0 = io[base + tid] + bias[tid];
  float x1 = io[base + 256 + tid] + bias[256 + tid];
  for (int s = 0; s < S; ++s) {
    x0 += part[(size_t)s * (S_ * D_) + base + tid];
    x1 += part[(size_t)s * (S_ * D_) + base + 256 + tid];
  }
  __shared__ float redA[4], redB[4];
  float s = x0 + x1;
#pragma unroll
  for (int off = 32; off > 0; off >>= 1) s += __shfl_down(s, off);
  if ((tid & 63) == 0) redA[tid >> 6] = s;
  __syncthreads();
  const float mu = (redA[0] + redA[1] + redA[2] + redA[3]) * (1.f / 512.f);
  const float d0 = x0 - mu, d1 = x1 - mu;
  float qv = d0 * d0 + d1 * d1;
#pragma unroll
  for (int off = 32; off > 0; off >>= 1) qv += __shfl_down(qv, off);
  if ((tid & 63) == 0) redB[tid >> 6] = qv;
  __syncthreads();
  const float var = (redB[0] + redB[1] + redB[2] + redB[3]) * (1.f / 512.f);
  const float inv = rsqrtf(var + 1e-5f);
  io[base + tid] = d0 * inv * g[tid] + b[tid];
  io[base + 256 + tid] = d1 * inv * g[256 + tid] + b[256 + tid];
}

// ---------------- attention (one block per (query, head)) ------------------
__global__ __launch_bounds__(256) void attn_kernel(const float* __restrict__ qkv,
                                                   float* __restrict__ o) {
  const int sq = blockIdx.x;
  const int h = blockIdx.y;
  const int tid = threadIdx.x;
  __shared__ __align__(16) float qv[64];
  __shared__ float sc[S_];
  __shared__ float redA[4], redB[4];
  __shared__ float pv[4][64];
  if (tid < 64) qv[tid] = qkv[(size_t)sq * 1536 + h * 64 + tid];
  __syncthreads();
  for (int j = tid; j < S_; j += 256) {
    const float4* kr =
        reinterpret_cast<const float4*>(&qkv[(size_t)j * 1536 + D_ + h * 64]);
    const float4* qr = reinterpret_cast<const float4*>(qv);
    float acc = 0.f;
#pragma unroll
    for (int d = 0; d < 16; ++d) {
      const float4 kk = kr[d], qq = qr[d];
      acc += kk.x * qq.x + kk.y * qq.y + kk.z * qq.z + kk.w * qq.w;
    }
    sc[j] = acc * 0.125f;
  }
  __syncthreads();
  float lm = -1e30f;
  for (int j = tid; j < S_; j += 256) lm = fmaxf(lm, sc[j]);
#pragma unroll
  for (int off = 32; off > 0; off >>= 1) lm = fmaxf(lm, __shfl_down(lm, off));
  if ((tid & 63) == 0) redA[tid >> 6] = lm;
  __syncthreads();
  const float M = fmaxf(fmaxf(redA[0], redA[1]), fmaxf(redA[2], redA[3]));
  float ls = 0.f;
  for (int j = tid; j < S_; j += 256) {
    const float p = __expf(sc[j] - M);
    sc[j] = p;
    ls += p;
  }
#pragma unroll
  for (int off = 32; off > 0; off >>= 1) ls += __shfl_down(ls, off);
  if ((tid & 63) == 0) redB[tid >> 6] = ls;
  __syncthreads();
  const float invS = 1.f / (redB[0] + redB[1] + redB[2] + redB[3]);
  const int d = tid & 63;
  const int ch = tid >> 6;
  float acc = 0.f;
  for (int j = ch; j < S_; j += 4)
    acc += sc[j] * qkv[(size_t)j * 1536 + 2 * D_ + h * 64 + d];
  pv[ch][d] = acc;
  __syncthreads();
  if (tid < 64)
    o[(size_t)sq * D_ + h * 64 + tid] =
        (pv[0][tid] + pv[1][tid] + pv[2][tid] + pv[3][tid]) * invS;
}

// ---------------- output head GEMV (split-d partials) -----------------------
__global__ __launch_bounds__(256) void gemv_kernel(const float* __restrict__ src0,
                                                   const float* __restrict__ out_w,
                                                   float* __restrict__ parts) {
  const int jc = blockIdx.x;
  const int dc = blockIdx.y;
  const int tid = threadIdx.x;
  __shared__ __align__(16) float s0[64];
  if (tid < 64) s0[tid] = src0[dc * 64 + tid];
  __syncthreads();
  const int j0 = jc * 1024 + tid * 4;
  float4 acc = make_float4(0.f, 0.f, 0.f, 0.f);
  for (int d = 0; d < 64; ++d) {
    const float sv = s0[d];
    const float4 w = *reinterpret_cast<const float4*>(
        &out_w[(size_t)(dc * 64 + d) * 65536 + j0]);
    acc.x += sv * w.x;
    acc.y += sv * w.y;
    acc.z += sv * w.z;
    acc.w += sv * w.w;
  }
  *reinterpret_cast<float4*>(&parts[(size_t)dc * 65536 + j0]) = acc;
}

__global__ __launch_bounds__(256) void logits_reduce_kernel(
    const float* __restrict__ parts, const float* __restrict__ out_b,
    float* __restrict__ logits) {
  const int j = (blockIdx.x * 256 + threadIdx.x) * 4;
  float4 acc = *reinterpret_cast<const float4*>(&out_b[j]);
#pragma unroll
  for (int p = 0; p < 8; ++p) {
    const float4 v =
        *reinterpret_cast<const float4*>(&parts[(size_t)p * 65536 + j]);
    acc.x += v.x;
    acc.y += v.y;
    acc.z += v.z;
    acc.w += v.w;
  }
  *reinterpret_cast<float4*>(&logits[j]) = acc;
}

// ---------------- sinkhorn (rank-1 reformulation) ---------------------------
__global__ __launch_bounds__(1024) void sinkhorn_kernel(
    const float* __restrict__ logits, float* __restrict__ out) {
  const int tid = threadIdx.x;
  const int tx = tid & 31;
  const int ty = tid >> 5;
  const int i0 = ty * 8, j0 = tx * 8;
  float E[8][8];
#pragma unroll
  for (int ii = 0; ii < 8; ++ii) {
    const float4 a =
        *reinterpret_cast<const float4*>(&logits[(i0 + ii) * 256 + j0]);
    const float4 b =
        *reinterpret_cast<const float4*>(&logits[(i0 + ii) * 256 + j0 + 4]);
    E[ii][0] = __expf(a.x);
    E[ii][1] = __expf(a.y);
    E[ii][2] = __expf(a.z);
    E[ii][3] = __expf(a.w);
    E[ii][4] = __expf(b.x);
    E[ii][5] = __expf(b.y);
    E[ii][6] = __expf(b.z);
    E[ii][7] = __expf(b.w);
  }
  __shared__ float part[32][8][32];
  __shared__ int partI[32][8][32];
  __shared__ float uu[256];
  __shared__ float vv[256];
  __shared__ int amax[256];
  if (tid < 256) uu[tid] = 1.f;
  __syncthreads();
  for (int it = 0; it < 20; ++it) {
    float ul[8];
#pragma unroll
    for (int ii = 0; ii < 8; ++ii) ul[ii] = uu[i0 + ii];
#pragma unroll
    for (int jj = 0; jj < 8; ++jj) {
      float s = 0.f;
#pragma unroll
      for (int ii = 0; ii < 8; ++ii) s += E[ii][jj] * ul[ii];
      part[ty][jj][tx] = s;
    }
    __syncthreads();
    if (tid < 256) {
      const int jj = tid >> 5, txr = tid & 31;
      float s = 0.f;
#pragma unroll
      for (int pp = 0; pp < 32; ++pp) s += part[pp][jj][txr];
      vv[txr * 8 + jj] = 1.f / s;
    }
    __syncthreads();
    float vl[8];
#pragma unroll
    for (int jj = 0; jj < 8; ++jj) vl[jj] = vv[j0 + jj];
#pragma unroll
    for (int ii = 0; ii < 8; ++ii) {
      float s = 0.f;
#pragma unroll
      for (int jj = 0; jj < 8; ++jj) s += E[ii][jj] * vl[jj];
      part[ty][ii][tx] = s;
    }
    __syncthreads();
    if (tid < 256) {
      const int i = tid;
      float s = 0.f;
#pragma unroll
      for (int pp = 0; pp < 32; ++pp) {
        const int pr = (pp + i) & 31;
        s += part[i >> 3][i & 7][pr];
      }
      uu[i] = 1.f / s;
    }
    __syncthreads();
  }
  float ul[8], vl[8];
#pragma unroll
  for (int ii = 0; ii < 8; ++ii) ul[ii] = uu[i0 + ii];
#pragma unroll
  for (int jj = 0; jj < 8; ++jj) vl[jj] = vv[j0 + jj];
#pragma unroll
  for (int ii = 0; ii < 8; ++ii) {
    float vals[8];
    float best = -1.f;
    int bidx = 0;
#pragma unroll
    for (int jj = 0; jj < 8; ++jj) {
      const float pv = E[ii][jj] * ul[ii] * vl[jj];
      vals[jj] = pv;
      if (pv > best) {
        best = pv;
        bidx = j0 + jj;
      }
    }
    *reinterpret_cast<float4*>(&out[(i0 + ii) * 256 + j0]) =
        make_float4(vals[0], vals[1], vals[2], vals[3]);
    *reinterpret_cast<float4*>(&out[(i0 + ii) * 256 + j0 + 4]) =
        make_float4(vals[4], vals[5], vals[6], vals[7]);
    part[ty][ii][tx] = best;
    partI[ty][ii][tx] = bidx;
  }
  __syncthreads();
  if (tid < 256) {
    const int i = tid;
    float best = -1.f;
    int bidx = 1 << 30;
#pragma unroll
    for (int pp = 0; pp < 32; ++pp) {
      const int pr = (pp + i) & 31;
      const float v = part[i >> 3][i & 7][pr];
      const int ix = partI[i >> 3][i & 7][pr];
      if (v > best || (v == best && ix < bidx)) {
        best = v;
        bidx = ix;
      }
    }
    amax[i] = bidx;
  }
  __syncthreads();
#pragma unroll
  for (int ii = 0; ii < 8; ++ii) {
    const int am = amax[i0 + ii];
    float4 h0, h1;
    h0.x = (j0 + 0 == am) ? 1.f : 0.f;
    h0.y = (j0 + 1 == am) ? 1.f : 0.f;
    h0.z = (j0 + 2 == am) ? 1.f : 0.f;
    h0.w = (j0 + 3 == am) ? 1.f : 0.f;
    h1.x = (j0 + 4 == am) ? 1.f : 0.f;
    h1.y = (j0 + 5 == am) ? 1.f : 0.f;
    h1.z = (j0 + 6 == am) ? 1.f : 0.f;
    h1.w = (j0 + 7 == am) ? 1.f : 0.f;
    *reinterpret_cast<float4*>(&out[65536 + (i0 + ii) * 256 + j0]) = h0;
    *reinterpret_cast<float4*>(&out[65536 + (i0 + ii) * 256 + j0 + 4]) = h1;
  }
}

// ---------------- host-side launch ------------------------------------------
extern "C" void kernel_launch(void* const* d_in, const int* in_sizes, int n_in,
                              void* d_out, int out_size, void* d_ws,
                              size_t ws_size, hipStream_t stream) {
  (void)in_sizes;
  (void)n_in;
  (void)out_size;
  (void)ws_size;
  const float* in_x = (const float*)d_in[0];
  const float* emb_w = (const float*)d_in[1];
  const float* emb_b = (const float*)d_in[2];
  const float* pos_emb = (const float*)d_in[3];
  const float* cls_emb = (const float*)d_in[4];
  const float* ipw = (const float*)d_in[5];
  const float* ipb = (const float*)d_in[6];
  const float* aow = (const float*)d_in[7];
  const float* aob = (const float*)d_in[8];
  const float* fw1 = (const float*)d_in[9];
  const float* fb1 = (const float*)d_in[10];
  const float* fw2 = (const float*)d_in[11];
  const float* fb2 = (const float*)d_in[12];
  const float* ln1g = (const float*)d_in[13];
  const float* ln1b = (const float*)d_in[14];
  const float* ln2g = (const float*)d_in[15];
  const float* ln2b = (const float*)d_in[16];
  const float* out_w = (const float*)d_in[17];
  const float* out_b = (const float*)d_in[18];
  float* out = (float*)d_out;
  float* ws = (float*)d_ws;

  float* src = ws;               // 131584
  float* qkv = ws + 131584;      // 394752
  float* attnO = ws + 526336;    // 131584
  float* ffh = ws + 657920;      // 526336
  float* logits = ws + 1184256;  // 65536
  float* part = ws + 1249792;    // max 8*526336
  float* gparts = part;

  embed_kernel<<<dim3(S_), dim3(256), 0, stream>>>(in_x, emb_w, emb_b, pos_emb,
                                                   cls_emb, src);
  for (int l = 0; l < 4; ++l) {
    // qkv: M=257 N=1536 K=512, splitK8 (kslice 64, nt=2)
    gemm_mfma<true><<<dim3(24 * MB_ * 8), dim3(256), 0, stream>>>(
        src, ipw + (size_t)l * 1536 * 512, part, S_, 1536, 512, 64, 24,
        S_ * 1536);
    reduce_elem<<<dim3(386), dim3(256), 0, stream>>>(part, ipb + l * 1536, qkv,
                                                     S_ * 1536, 1536, 8, 0);
    attn_kernel<<<dim3(S_, 8), dim3(256), 0, stream>>>(qkv, attnO);
    // proj: N=512 K=512, splitK16 (kslice 32, nt=1)
    gemm_mfma<true><<<dim3(8 * MB_ * 16), dim3(256), 0, stream>>>(
        attnO, aow + (size_t)l * 512 * 512, part, S_, 512, 512, 32, 8,
        S_ * D_);
    reduce_ln<<<dim3(S_), dim3(256), 0, stream>>>(part, aob + l * 512, src,
                                                  ln1g + l * 512,
                                                  ln1b + l * 512, 16);
    // ff1: N=2048 K=512, splitK8 (kslice 64, nt=2)
    gemm_mfma<false><<<dim3(32 * MB_ * 8), dim3(256), 0, stream>>>(
        src, fw1 + (size_t)l * 512 * 2048, part, S_, 2048, 512, 64, 32,
        S_ * 2048);
    reduce_elem<<<dim3(514), dim3(256), 0, stream>>>(part, fb1 + l * 2048, ffh,
                                                     S_ * 2048, 2048, 8, 1);
    // ff2: N=512 K=2048, splitK16 (kslice 128, nt=4)
    gemm_mfma<false><<<dim3(8 * MB_ * 16), dim3(256), 0, stream>>>(
        ffh, fw2 + (size_t)l * 2048 * 512, part, S_, 512, 2048, 128, 8,
        S_ * D_);
    reduce_ln<<<dim3(S_), dim3(256), 0, stream>>>(part, fb2 + l * 512, src,
                                                  ln2g + l * 512,
                                                  ln2b + l * 512, 16);
  }
  gemv_kernel<<<dim3(64, 8), dim3(256), 0, stream>>>(src, out_w, gparts);
  logits_reduce_kernel<<<dim3(64), dim3(256), 0, stream>>>(gparts, out_b,
                                                           logits);
  sinkhorn_kernel<<<dim3(1), dim3(1024), 0, stream>>>(logits, out);
}